// Round 1
// baseline (838.004 us; speedup 1.0000x reference)
//
#include <hip/hip_runtime.h>

// DiffeomorphicLearnerTorch, R7.
// R4-R6 plateaued k_flash at ~40us vs ~9us operand floor: the producer->sP(LDS)
// ->consumer pipeline is latency-bound (dependent MFMA chain -> exp -> LDS
// round trip -> barrier, 2-deep buffer). R7 deletes the split: each wave
// computes S^T = mfma(A=Zj, B=Zi) so its P-row is LANE-LOCAL (i in lanes,
// j in regs), applies ei*ej*exp in-register, packs via v_cvt_pk_bf16_f32 +
// v_permlane32_swap_b32 (T12), and feeds PV's MFMA A-operand directly.
// No sP, no producer/consumer coupling; one barrier per 32-j tile for the
// double-buffered Zj LDS stage (global_load_lds, 16KB/tile).
// Wave = 32 i-rows x 128 d-cols; block = 4 waves (64 i x 256 d);
// grid (8 chunks, 64 i-blocks) = 512 blocks, 2 blocks/CU (VGPR-capped).
// Frag-linear layouts (verified R4/R5):
//   Zf  [128 jblk][16 ks][64 lane]x8 bf16   (A and B share lane mapping)
//   ATf [t][8 dblk][256 jb][64 lane]x8 bf16
// eperm = erow permuted to S^T reg order: eperm[jt*32+lhi*16+c] = erow[jt*32+crow(c,lhi)].

#define N_PTS 4096
#define DIM   256
#define DT_C  0.125f
#define C1    (1.0f/512.0f)
#define C2    (1.0f/256.0f)

typedef __bf16 bf16x8 __attribute__((ext_vector_type(8)));
typedef float  f32x16 __attribute__((ext_vector_type(16)));
typedef float  f32x4v __attribute__((ext_vector_type(4)));
typedef unsigned int   u32x4 __attribute__((ext_vector_type(4)));
typedef unsigned short u16x8 __attribute__((ext_vector_type(8)));

__device__ __forceinline__ unsigned short f2bf(float f) {
  unsigned int u = __builtin_bit_cast(unsigned int, f);
  u += 0x7fffu + ((u >> 16) & 1u);          // RNE
  return (unsigned short)(u >> 16);
}
__device__ __forceinline__ float bf2f(unsigned short s) {
  unsigned int u = ((unsigned int)s) << 16;
  return __builtin_bit_cast(float, u);
}

typedef __attribute__((address_space(1))) const unsigned int gas_u32;
typedef __attribute__((address_space(3))) unsigned int las_u32;
__device__ __forceinline__ void gload_lds16(const void* g, void* l) {
  __builtin_amdgcn_global_load_lds((gas_u32*)g, (las_u32*)l, 16, 0, 0);
}

// ---- ATf: A[t][4096][256] f32 -> frag-linear bf16 B-operand tiles ----
__global__ __launch_bounds__(256) void k_prep(const float* __restrict__ A,
                                              unsigned short* __restrict__ ATf) {
  __shared__ float sT[64][36];
  const int jgrp = blockIdx.x, ds = blockIdx.y, t = blockIdx.z;
  const int tid = threadIdx.x;
  const float* Ab = A + (size_t)t * N_PTS * DIM;
  {
    const int j_l = tid >> 2, dq = tid & 3;
    const float* src = Ab + (size_t)(jgrp * 64 + j_l) * DIM + ds * 32 + dq * 8;
    f32x4v v0 = *(const f32x4v*)src, v1 = *(const f32x4v*)(src + 4);
    *(f32x4v*)&sT[j_l][dq * 8] = v0;
    *(f32x4v*)&sT[j_l][dq * 8 + 4] = v1;
  }
  __syncthreads();
  const int jb_l = tid >> 6, l = tid & 63, l31 = l & 31, lhi = l >> 5;
  u16x8 o;
#pragma unroll
  for (int e = 0; e < 8; ++e) o[e] = f2bf(sT[jb_l * 16 + lhi * 8 + e][l31]);
  unsigned short* dst = ATf + (size_t)t * (8 * 256 * 64 * 8)
                      + ((size_t)(ds * 256 + jgrp * 4 + jb_l) * 64 + l) * 8;
  *(u16x8*)dst = o;
}

// eperm index for row r
__device__ __forceinline__ int pidx(int r) {
  const int jj = r & 31;
  return (r & ~31) | (((jj >> 2) & 1) << 4) | (((jj >> 3) & 3) << 2) | (jj & 3);
}

// ---- init: X -> Zf frags + erow + eperm ----
__global__ __launch_bounds__(256) void k_init(const float* __restrict__ X,
                                              unsigned short* __restrict__ Zf,
                                              float* __restrict__ erow,
                                              float* __restrict__ eperm) {
  const int tid = threadIdx.x;
  const int r = blockIdx.x * 8 + (tid >> 5), o = tid & 31;
  const size_t base = (size_t)r * DIM + o * 8;
  f32x4v z0 = *(const f32x4v*)(X + base), z1 = *(const f32x4v*)(X + base + 4);
  u16x8 zb; float s = 0.f;
#pragma unroll
  for (int i = 0; i < 4; ++i) { zb[i] = f2bf(z0[i]); zb[4 + i] = f2bf(z1[i]);
                                s += z0[i] * z0[i] + z1[i] * z1[i]; }
  *(u16x8*)(Zf + ((size_t)((r >> 5) * 16 + (o >> 1)) * 64 + (o & 1) * 32 + (r & 31)) * 8) = zb;
#pragma unroll
  for (int d = 16; d > 0; d >>= 1) s += __shfl_down(s, d, 32);
  if (o == 0) { const float e = __expf(-s * C1); erow[r] = e; eperm[pidx(r)] = e; }
}

// ---- fused flash, R7: per-wave S^T -> in-register P -> PV ----
// grid (8 chunks, 64 i-blocks), 256 thr = 4 waves: ig=wid>>1 (32 i-rows),
// dh=wid&1 (128 d-cols). Zi resident (16 frags = 64 VGPR). Zj double-buffered
// in LDS (16KB/tile, global_load_lds). ATf b-frags from L2. One barrier/tile.
__global__ __launch_bounds__(256, 2) void k_flash(
    const unsigned short* __restrict__ Zf, const float* __restrict__ erow,
    const float* __restrict__ eperm,
    const unsigned short* __restrict__ ATf_t,
    const float* __restrict__ Aaff_t,
    unsigned short* __restrict__ Opart) {
  __shared__ __align__(16) unsigned short sZj[2][16 * 64 * 8];  // 2 x 16KB

  const int tid = threadIdx.x, lane = tid & 63, wid = tid >> 6;
  const int l31 = lane & 31, lhi = lane >> 5;
  const int ig = wid >> 1, dh = wid & 1;
  const int chunk = blockIdx.x;
  const int i0 = blockIdx.y * 64;

  // stage tile 0 of this chunk's Zj into buf 0 (16KB: 4 x 16B per thread)
  {
    const unsigned short* src = Zf + (size_t)(chunk * 16) * 8192;
#pragma unroll
    for (int p = 0; p < 4; ++p)
      gload_lds16(src + (size_t)(p * 256 + tid) * 8, &sZj[0][(p * 256 + tid) * 8]);
  }

  // resident Zi frags: wave's 32 i-rows x K=256
  const unsigned short* zib = Zf + (size_t)(blockIdx.y * 2 + ig) * 8192;
  u32x4 zi[16];
#pragma unroll
  for (int ks = 0; ks < 16; ++ks)
    zi[ks] = *(const u32x4*)(zib + (size_t)ks * 512 + lane * 8);

  const float eI = erow[i0 + ig * 32 + l31];

  // O init + affine slice (ksg = chunk*2+q, unscaled; summed across chunks)
  f32x16 O[4];
#pragma unroll
  for (int ct = 0; ct < 4; ++ct)
#pragma unroll
    for (int i = 0; i < 16; ++i) O[ct][i] = 0.f;
#pragma unroll
  for (int q = 0; q < 2; ++q) {
    const int ksg = chunk * 2 + q;
    const bf16x8 a = __builtin_bit_cast(bf16x8, zi[ksg]);
#pragma unroll
    for (int ct = 0; ct < 4; ++ct) {
      const int d = dh * 128 + ct * 32 + l31;
      const float* bp = Aaff_t + (size_t)d * DIM + ksg * 16 + lhi * 8;
      f32x4v f0 = *(const f32x4v*)bp, f1 = *(const f32x4v*)(bp + 4);
      u16x8 tb;
#pragma unroll
      for (int i = 0; i < 4; ++i) { tb[i] = f2bf(f0[i]); tb[4 + i] = f2bf(f1[i]); }
      O[ct] = __builtin_amdgcn_mfma_f32_32x32x16_bf16(
          a, __builtin_bit_cast(bf16x8, tb), O[ct], 0, 0, 0);
    }
  }
  __syncthreads();

  const float* epc = eperm + (size_t)chunk * 512 + lhi * 16;
  const unsigned short* atb =
      ATf_t + ((size_t)(dh * 4 * 256 + chunk * 32) * 64 + lane) * 8;

  for (int n = 0; n < 16; ++n) {
    const int cur = n & 1;
    // prefetch next Zj tile into other buffer (overlaps this tile's compute)
    if (n < 15) {
      const unsigned short* src = Zf + (size_t)(chunk * 16 + n + 1) * 8192;
#pragma unroll
      for (int p = 0; p < 4; ++p)
        gload_lds16(src + (size_t)(p * 256 + tid) * 8,
                    &sZj[cur ^ 1][(p * 256 + tid) * 8]);
    }
    // hoist the 8 ATf b-frags (L2) + ej (broadcast)
    u32x4 bw[8];
#pragma unroll
    for (int ct = 0; ct < 4; ++ct)
#pragma unroll
      for (int q = 0; q < 2; ++q)
        bw[ct * 2 + q] = *(const u32x4*)(atb + ((size_t)ct * 256 + n * 2 + q) * 512);
    f32x4v e0 = *(const f32x4v*)(epc + n * 32);
    f32x4v e1 = *(const f32x4v*)(epc + n * 32 + 4);
    f32x4v e2 = *(const f32x4v*)(epc + n * 32 + 8);
    f32x4v e3 = *(const f32x4v*)(epc + n * 32 + 12);

    // S^T = Zj @ Zi^T : A=Zj (LDS), B=Zi (regs); 2 chains to halve dep depth
    f32x16 Sa, Sb;
#pragma unroll
    for (int i = 0; i < 16; ++i) { Sa[i] = 0.f; Sb[i] = 0.f; }
#pragma unroll
    for (int ks = 0; ks < 16; ks += 2) {
      bf16x8 a0 = *(const bf16x8*)(&sZj[cur][(ks + 0) * 512 + lane * 8]);
      bf16x8 a1 = *(const bf16x8*)(&sZj[cur][(ks + 1) * 512 + lane * 8]);
      Sa = __builtin_amdgcn_mfma_f32_32x32x16_bf16(
          a0, __builtin_bit_cast(bf16x8, zi[ks + 0]), Sa, 0, 0, 0);
      Sb = __builtin_amdgcn_mfma_f32_32x32x16_bf16(
          a1, __builtin_bit_cast(bf16x8, zi[ks + 1]), Sb, 0, 0, 0);
    }

    // P^T in-register: lane=(i,lhi), reg c -> j = n*32 + (c&3)+8*(c>>2)+4*lhi
    float p[16];
#pragma unroll
    for (int c = 0; c < 16; ++c) {
      const float ej = (c < 4) ? e0[c] : (c < 8) ? e1[c - 4]
                     : (c < 12) ? e2[c - 8] : e3[c - 12];
      p[c] = eI * ej * __expf((Sa[c] + Sb[c]) * C2);
    }
    // pack pairs to bf16 dwords: dw[g] = {p[4g],p[4g+1]},{p[4g+2],p[4g+3]}
    unsigned int dw[4][2];
#pragma unroll
    for (int g = 0; g < 4; ++g) {
      asm("v_cvt_pk_bf16_f32 %0, %1, %2" : "=v"(dw[g][0]) : "v"(p[4 * g + 0]), "v"(p[4 * g + 1]));
      asm("v_cvt_pk_bf16_f32 %0, %1, %2" : "=v"(dw[g][1]) : "v"(p[4 * g + 2]), "v"(p[4 * g + 3]));
    }
    // permlane32_swap: x_new={x_lo,y_lo} -> frag words (e0..3), y_new={x_hi,y_hi} -> (e4..7)
#pragma unroll
    for (int q = 0; q < 2; ++q) {
      auto r0 = __builtin_amdgcn_permlane32_swap(dw[2 * q][0], dw[2 * q + 1][0], false, false);
      auto r1 = __builtin_amdgcn_permlane32_swap(dw[2 * q][1], dw[2 * q + 1][1], false, false);
      u32x4 paw; paw[0] = r0[0]; paw[1] = r1[0]; paw[2] = r0[1]; paw[3] = r1[1];
      const bf16x8 pa = __builtin_bit_cast(bf16x8, paw);
#pragma unroll
      for (int ct = 0; ct < 4; ++ct)
        O[ct] = __builtin_amdgcn_mfma_f32_32x32x16_bf16(
            pa, __builtin_bit_cast(bf16x8, bw[ct * 2 + q]), O[ct], 0, 0, 0);
    }
    __syncthreads();  // next tile staged (vmcnt drain) + all reads of cur done
  }

  // epilogue -> Opart[chunk] bf16 (P already carries ei*ej)
  unsigned short* ob = Opart + (size_t)chunk * N_PTS * DIM
                     + (size_t)(i0 + ig * 32) * DIM + dh * 128 + l31;
#pragma unroll
  for (int ct = 0; ct < 4; ++ct)
#pragma unroll
    for (int c = 0; c < 16; ++c) {
      const int row = 4 * lhi + (c & 3) + 8 * (c >> 2);
      ob[(size_t)row * DIM + ct * 32] = f2bf(O[ct][c]);
    }
}

// ---- update: Z += DT*(sum partials + baff); emit Zf frags + erow + eperm ----
__global__ __launch_bounds__(256) void k_update(const float* __restrict__ Zin,
                                                const unsigned short* __restrict__ Opart,
                                                const float* __restrict__ baff_t,
                                                float* __restrict__ Zout,
                                                unsigned short* __restrict__ Zf,
                                                float* __restrict__ erow,
                                                float* __restrict__ eperm) {
  const int tid = threadIdx.x;
  const int r = blockIdx.x * 8 + (tid >> 5), o = tid & 31;
  const size_t base = (size_t)r * DIM + o * 8;
  f32x4v z0 = *(const f32x4v*)(Zin + base), z1 = *(const f32x4v*)(Zin + base + 4);
  f32x4v s0 = *(const f32x4v*)(baff_t + o * 8), s1 = *(const f32x4v*)(baff_t + o * 8 + 4);
#pragma unroll
  for (int c = 0; c < 8; ++c) {
    u16x8 p = *(const u16x8*)(Opart + (size_t)c * N_PTS * DIM + base);
#pragma unroll
    for (int i = 0; i < 4; ++i) { s0[i] += bf2f(p[i]); s1[i] += bf2f(p[4 + i]); }
  }
  u16x8 zb; float sv = 0.f;
#pragma unroll
  for (int i = 0; i < 4; ++i) {
    z0[i] += DT_C * s0[i]; z1[i] += DT_C * s1[i];
    zb[i] = f2bf(z0[i]); zb[4 + i] = f2bf(z1[i]);
    sv += z0[i] * z0[i] + z1[i] * z1[i];
  }
  *(f32x4v*)(Zout + base) = z0;
  *(f32x4v*)(Zout + base + 4) = z1;
  *(u16x8*)(Zf + ((size_t)((r >> 5) * 16 + (o >> 1)) * 64 + (o & 1) * 32 + (r & 31)) * 8) = zb;
#pragma unroll
  for (int d = 16; d > 0; d >>= 1) sv += __shfl_down(sv, d, 32);
  if (o == 0) { const float e = __expf(-sv * C1); erow[r] = e; eperm[pidx(r)] = e; }
}

extern "C" void kernel_launch(void* const* d_in, const int* in_sizes, int n_in,
                              void* d_out, int out_size, void* d_ws, size_t ws_size,
                              hipStream_t stream) {
  const float* X    = (const float*)d_in[0];
  const float* A    = (const float*)d_in[1];
  const float* Aaff = (const float*)d_in[2];
  const float* baff = (const float*)d_in[3];
  float* out = (float*)d_out;

  char* w = (char*)d_ws;
  size_t off = 0;
  unsigned short* ATf = (unsigned short*)(w + off); off += (size_t)8 * 8 * 256 * 64 * 8 * 2; // 16 MiB
  unsigned short* Zf  = (unsigned short*)(w + off); off += (size_t)N_PTS * DIM * 2;          // 2 MiB
  float* erow  = (float*)(w + off); off += (size_t)N_PTS * 4;
  float* eperm = (float*)(w + off); off += (size_t)N_PTS * 4;
  float* Zf32 = (float*)(w + off); off += (size_t)N_PTS * DIM * 4;                           // 4 MiB
  unsigned short* Opart = (unsigned short*)(w + off); off += (size_t)8 * N_PTS * DIM * 2;    // 16 MiB
  (void)ws_size; (void)in_sizes; (void)n_in; (void)out_size;

  k_prep<<<dim3(64, 8, 8), 256, 0, stream>>>(A, ATf);
  k_init<<<512, 256, 0, stream>>>(X, Zf, erow, eperm);

  const float* zin = X;
  for (int t = 0; t < 8; ++t) {
    float* zout = (t == 7) ? out : Zf32;  // in-place safe after t=0
    k_flash<<<dim3(8, 64), 256, 0, stream>>>(
        Zf, erow, eperm, ATf + (size_t)t * (8 * 256 * 64 * 8), Aaff + (size_t)t * DIM * DIM, Opart);
    k_update<<<512, 256, 0, stream>>>(zin, Opart, baff + (size_t)t * DIM, zout, Zf, erow, eperm);
    zin = zout;
  }
}

// Round 2
// 459.430 us; speedup vs baseline: 1.8240x; 1.8240x over previous
//
#include <hip/hip_runtime.h>

// DiffeomorphicLearnerTorch, R8.
// R7 (same structure) regressed to 100us/launch: VGPR_Count=68 + 113MB
// FETCH/launch = register arrays demoted to scratch. Root cause: affine
// prologue indexed zi[chunk*2+q] with RUNTIME chunk (rule #20) -> whole
// zi[16] array in local memory -> every S-MFMA B-operand a scratch load.
// R8: affine a-frags read from GLOBAL (runtime offset into memory is fine);
// all register-array indices statically unrolled. Also trimmed peak VGPR
// (~215): no p[16] staging, plain-C bf16 pack (m240: asm cvt_pk hurts),
// bw/e hoists kept but scheduled after/before the S-chain.
// Structure (R7): each wave computes S^T = mfma(A=Zj_lds, B=Zi_regs) so its
// P-row is LANE-LOCAL; ei*ej*exp in-register; pack + permlane32_swap (T12)
// feeds PV's MFMA A-operand directly. No sP, one barrier per 32-j tile,
// Zj double-buffered via global_load_lds (16KB/tile).
// Wave = 32 i-rows x 128 d-cols; block = 4 waves (64 i x 256 d);
// grid (8 chunks, 64 i-blocks) = 512 blocks, 2 blocks/CU.
// Frag-linear layouts (verified R4/R5):
//   Zf  [128 jblk][16 ks][64 lane]x8 bf16   (A and B share lane mapping)
//   ATf [t][8 dblk][256 jb][64 lane]x8 bf16
// eperm = erow permuted to S^T reg order: eperm[jt*32+lhi*16+c] = erow[jt*32+crow(c,lhi)].

#define N_PTS 4096
#define DIM   256
#define DT_C  0.125f
#define C1    (1.0f/512.0f)
#define C2    (1.0f/256.0f)

typedef __bf16 bf16x8 __attribute__((ext_vector_type(8)));
typedef float  f32x16 __attribute__((ext_vector_type(16)));
typedef float  f32x4v __attribute__((ext_vector_type(4)));
typedef unsigned int   u32x4 __attribute__((ext_vector_type(4)));
typedef unsigned short u16x8 __attribute__((ext_vector_type(8)));

__device__ __forceinline__ unsigned short f2bf(float f) {
  unsigned int u = __builtin_bit_cast(unsigned int, f);
  u += 0x7fffu + ((u >> 16) & 1u);          // RNE
  return (unsigned short)(u >> 16);
}
__device__ __forceinline__ float bf2f(unsigned short s) {
  unsigned int u = ((unsigned int)s) << 16;
  return __builtin_bit_cast(float, u);
}

typedef __attribute__((address_space(1))) const unsigned int gas_u32;
typedef __attribute__((address_space(3))) unsigned int las_u32;
__device__ __forceinline__ void gload_lds16(const void* g, void* l) {
  __builtin_amdgcn_global_load_lds((gas_u32*)g, (las_u32*)l, 16, 0, 0);
}

// ---- ATf: A[t][4096][256] f32 -> frag-linear bf16 B-operand tiles ----
__global__ __launch_bounds__(256) void k_prep(const float* __restrict__ A,
                                              unsigned short* __restrict__ ATf) {
  __shared__ float sT[64][36];
  const int jgrp = blockIdx.x, ds = blockIdx.y, t = blockIdx.z;
  const int tid = threadIdx.x;
  const float* Ab = A + (size_t)t * N_PTS * DIM;
  {
    const int j_l = tid >> 2, dq = tid & 3;
    const float* src = Ab + (size_t)(jgrp * 64 + j_l) * DIM + ds * 32 + dq * 8;
    f32x4v v0 = *(const f32x4v*)src, v1 = *(const f32x4v*)(src + 4);
    *(f32x4v*)&sT[j_l][dq * 8] = v0;
    *(f32x4v*)&sT[j_l][dq * 8 + 4] = v1;
  }
  __syncthreads();
  const int jb_l = tid >> 6, l = tid & 63, l31 = l & 31, lhi = l >> 5;
  u16x8 o;
#pragma unroll
  for (int e = 0; e < 8; ++e) o[e] = f2bf(sT[jb_l * 16 + lhi * 8 + e][l31]);
  unsigned short* dst = ATf + (size_t)t * (8 * 256 * 64 * 8)
                      + ((size_t)(ds * 256 + jgrp * 4 + jb_l) * 64 + l) * 8;
  *(u16x8*)dst = o;
}

// eperm index for row r
__device__ __forceinline__ int pidx(int r) {
  const int jj = r & 31;
  return (r & ~31) | (((jj >> 2) & 1) << 4) | (((jj >> 3) & 3) << 2) | (jj & 3);
}

// ---- init: X -> Zf frags + erow + eperm ----
__global__ __launch_bounds__(256) void k_init(const float* __restrict__ X,
                                              unsigned short* __restrict__ Zf,
                                              float* __restrict__ erow,
                                              float* __restrict__ eperm) {
  const int tid = threadIdx.x;
  const int r = blockIdx.x * 8 + (tid >> 5), o = tid & 31;
  const size_t base = (size_t)r * DIM + o * 8;
  f32x4v z0 = *(const f32x4v*)(X + base), z1 = *(const f32x4v*)(X + base + 4);
  u16x8 zb; float s = 0.f;
#pragma unroll
  for (int i = 0; i < 4; ++i) { zb[i] = f2bf(z0[i]); zb[4 + i] = f2bf(z1[i]);
                                s += z0[i] * z0[i] + z1[i] * z1[i]; }
  *(u16x8*)(Zf + ((size_t)((r >> 5) * 16 + (o >> 1)) * 64 + (o & 1) * 32 + (r & 31)) * 8) = zb;
#pragma unroll
  for (int d = 16; d > 0; d >>= 1) s += __shfl_down(s, d, 32);
  if (o == 0) { const float e = __expf(-s * C1); erow[r] = e; eperm[pidx(r)] = e; }
}

// ---- fused flash, R8: per-wave S^T -> in-register P -> PV ----
// grid (8 chunks, 64 i-blocks), 256 thr = 4 waves: ig=wid>>1 (32 i-rows),
// dh=wid&1 (128 d-cols). Zi resident in VGPRs (ALL indices static!).
// Zj double-buffered in LDS (16KB/tile, global_load_lds). One barrier/tile.
__global__ __launch_bounds__(256, 2) void k_flash(
    const unsigned short* __restrict__ Zf, const float* __restrict__ erow,
    const float* __restrict__ eperm,
    const unsigned short* __restrict__ ATf_t,
    const float* __restrict__ Aaff_t,
    unsigned short* __restrict__ Opart) {
  __shared__ __align__(16) unsigned short sZj[2][16 * 64 * 8];  // 2 x 16KB

  const int tid = threadIdx.x, lane = tid & 63, wid = tid >> 6;
  const int l31 = lane & 31, lhi = lane >> 5;
  const int ig = wid >> 1, dh = wid & 1;
  const int chunk = blockIdx.x;
  const int i0 = blockIdx.y * 64;

  // stage tile 0 of this chunk's Zj into buf 0 (16KB: 4 x 16B per thread)
  {
    const unsigned short* src = Zf + (size_t)(chunk * 16) * 8192;
#pragma unroll
    for (int p = 0; p < 4; ++p)
      gload_lds16(src + (size_t)(p * 256 + tid) * 8, &sZj[0][(p * 256 + tid) * 8]);
  }

  // resident Zi frags: wave's 32 i-rows x K=256 (static indices ONLY)
  const unsigned short* zib = Zf + (size_t)(blockIdx.y * 2 + ig) * 8192;
  u32x4 zi[16];
#pragma unroll
  for (int ks = 0; ks < 16; ++ks)
    zi[ks] = *(const u32x4*)(zib + (size_t)ks * 512 + lane * 8);

  const float eI = erow[i0 + ig * 32 + l31];

  // O init + affine slice (ksg = chunk*2+q, unscaled; summed across chunks).
  // NB: a-frag re-read from GLOBAL — zi[ksg] with runtime chunk would demote
  // the whole zi[] array to scratch (rule #20; this was R7's 2.5x regression).
  f32x16 O[4];
#pragma unroll
  for (int ct = 0; ct < 4; ++ct)
#pragma unroll
    for (int i = 0; i < 16; ++i) O[ct][i] = 0.f;
#pragma unroll
  for (int q = 0; q < 2; ++q) {
    const int ksg = chunk * 2 + q;
    const bf16x8 a = *(const bf16x8*)(zib + (size_t)ksg * 512 + lane * 8);
#pragma unroll
    for (int ct = 0; ct < 4; ++ct) {
      const int d = dh * 128 + ct * 32 + l31;
      const float* bp = Aaff_t + (size_t)d * DIM + ksg * 16 + lhi * 8;
      f32x4v f0 = *(const f32x4v*)bp, f1 = *(const f32x4v*)(bp + 4);
      u16x8 tb;
#pragma unroll
      for (int i = 0; i < 4; ++i) { tb[i] = f2bf(f0[i]); tb[4 + i] = f2bf(f1[i]); }
      O[ct] = __builtin_amdgcn_mfma_f32_32x32x16_bf16(
          a, __builtin_bit_cast(bf16x8, tb), O[ct], 0, 0, 0);
    }
  }
  __syncthreads();

  const float* epc = eperm + (size_t)chunk * 512 + lhi * 16;
  const unsigned short* atb =
      ATf_t + ((size_t)(dh * 4 * 256 + chunk * 32) * 64 + lane) * 8;

  for (int n = 0; n < 16; ++n) {
    const int cur = n & 1;
    // prefetch next Zj tile into other buffer (overlaps this tile's compute)
    if (n < 15) {
      const unsigned short* src = Zf + (size_t)(chunk * 16 + n + 1) * 8192;
#pragma unroll
      for (int p = 0; p < 4; ++p)
        gload_lds16(src + (size_t)(p * 256 + tid) * 8,
                    &sZj[cur ^ 1][(p * 256 + tid) * 8]);
    }
    // ej hoist (16 regs, live through S-chain; L2 latency hides under MFMAs)
    f32x4v e0 = *(const f32x4v*)(epc + n * 32);
    f32x4v e1 = *(const f32x4v*)(epc + n * 32 + 4);
    f32x4v e2 = *(const f32x4v*)(epc + n * 32 + 8);
    f32x4v e3 = *(const f32x4v*)(epc + n * 32 + 12);

    // S^T = Zj @ Zi^T : A=Zj (LDS), B=Zi (regs); 2 chains to halve dep depth
    f32x16 Sa, Sb;
#pragma unroll
    for (int i = 0; i < 16; ++i) { Sa[i] = 0.f; Sb[i] = 0.f; }
#pragma unroll
    for (int ks = 0; ks < 16; ks += 2) {
      bf16x8 a0 = *(const bf16x8*)(&sZj[cur][(ks + 0) * 512 + lane * 8]);
      bf16x8 a1 = *(const bf16x8*)(&sZj[cur][(ks + 1) * 512 + lane * 8]);
      Sa = __builtin_amdgcn_mfma_f32_32x32x16_bf16(
          a0, __builtin_bit_cast(bf16x8, zi[ks + 0]), Sa, 0, 0, 0);
      Sb = __builtin_amdgcn_mfma_f32_32x32x16_bf16(
          a1, __builtin_bit_cast(bf16x8, zi[ks + 1]), Sb, 0, 0, 0);
    }

    // ATf b-frags for both q halves; L2 latency hides under exp/pack VALU
    u32x4 bw[8];
#pragma unroll
    for (int ct = 0; ct < 4; ++ct)
#pragma unroll
      for (int q = 0; q < 2; ++q)
        bw[ct * 2 + q] = *(const u32x4*)(atb + ((size_t)ct * 256 + n * 2 + q) * 512);

    // P^T groupwise: lane=(i,lhi), reg c -> j = n*32 + (c&3)+8*(c>>2)+4*lhi
    unsigned int dw[4][2];
#pragma unroll
    for (int g = 0; g < 4; ++g) {
      const f32x4v ev = (g == 0) ? e0 : (g == 1) ? e1 : (g == 2) ? e2 : e3;
      const float p0 = eI * ev[0] * __expf((Sa[4 * g + 0] + Sb[4 * g + 0]) * C2);
      const float p1 = eI * ev[1] * __expf((Sa[4 * g + 1] + Sb[4 * g + 1]) * C2);
      const float p2 = eI * ev[2] * __expf((Sa[4 * g + 2] + Sb[4 * g + 2]) * C2);
      const float p3 = eI * ev[3] * __expf((Sa[4 * g + 3] + Sb[4 * g + 3]) * C2);
      dw[g][0] = (unsigned int)f2bf(p0) | ((unsigned int)f2bf(p1) << 16);
      dw[g][1] = (unsigned int)f2bf(p2) | ((unsigned int)f2bf(p3) << 16);
    }
    // permlane32_swap: x_new={x_lo,y_lo} -> frag words (e0..3), y_new -> (e4..7)
#pragma unroll
    for (int q = 0; q < 2; ++q) {
      auto r0 = __builtin_amdgcn_permlane32_swap(dw[2 * q][0], dw[2 * q + 1][0], false, false);
      auto r1 = __builtin_amdgcn_permlane32_swap(dw[2 * q][1], dw[2 * q + 1][1], false, false);
      u32x4 paw; paw[0] = r0[0]; paw[1] = r1[0]; paw[2] = r0[1]; paw[3] = r1[1];
      const bf16x8 pa = __builtin_bit_cast(bf16x8, paw);
#pragma unroll
      for (int ct = 0; ct < 4; ++ct)
        O[ct] = __builtin_amdgcn_mfma_f32_32x32x16_bf16(
            pa, __builtin_bit_cast(bf16x8, bw[ct * 2 + q]), O[ct], 0, 0, 0);
    }
    __syncthreads();  // next tile staged (vmcnt drain) + all reads of cur done
  }

  // epilogue -> Opart[chunk] bf16 (P already carries ei*ej)
  unsigned short* ob = Opart + (size_t)chunk * N_PTS * DIM
                     + (size_t)(i0 + ig * 32) * DIM + dh * 128 + l31;
#pragma unroll
  for (int ct = 0; ct < 4; ++ct)
#pragma unroll
    for (int c = 0; c < 16; ++c) {
      const int row = 4 * lhi + (c & 3) + 8 * (c >> 2);
      ob[(size_t)row * DIM + ct * 32] = f2bf(O[ct][c]);
    }
}

// ---- update: Z += DT*(sum partials + baff); emit Zf frags + erow + eperm ----
__global__ __launch_bounds__(256) void k_update(const float* __restrict__ Zin,
                                                const unsigned short* __restrict__ Opart,
                                                const float* __restrict__ baff_t,
                                                float* __restrict__ Zout,
                                                unsigned short* __restrict__ Zf,
                                                float* __restrict__ erow,
                                                float* __restrict__ eperm) {
  const int tid = threadIdx.x;
  const int r = blockIdx.x * 8 + (tid >> 5), o = tid & 31;
  const size_t base = (size_t)r * DIM + o * 8;
  f32x4v z0 = *(const f32x4v*)(Zin + base), z1 = *(const f32x4v*)(Zin + base + 4);
  f32x4v s0 = *(const f32x4v*)(baff_t + o * 8), s1 = *(const f32x4v*)(baff_t + o * 8 + 4);
#pragma unroll
  for (int c = 0; c < 8; ++c) {
    u16x8 p = *(const u16x8*)(Opart + (size_t)c * N_PTS * DIM + base);
#pragma unroll
    for (int i = 0; i < 4; ++i) { s0[i] += bf2f(p[i]); s1[i] += bf2f(p[4 + i]); }
  }
  u16x8 zb; float sv = 0.f;
#pragma unroll
  for (int i = 0; i < 4; ++i) {
    z0[i] += DT_C * s0[i]; z1[i] += DT_C * s1[i];
    zb[i] = f2bf(z0[i]); zb[4 + i] = f2bf(z1[i]);
    sv += z0[i] * z0[i] + z1[i] * z1[i];
  }
  *(f32x4v*)(Zout + base) = z0;
  *(f32x4v*)(Zout + base + 4) = z1;
  *(u16x8*)(Zf + ((size_t)((r >> 5) * 16 + (o >> 1)) * 64 + (o & 1) * 32 + (r & 31)) * 8) = zb;
#pragma unroll
  for (int d = 16; d > 0; d >>= 1) sv += __shfl_down(sv, d, 32);
  if (o == 0) { const float e = __expf(-sv * C1); erow[r] = e; eperm[pidx(r)] = e; }
}

extern "C" void kernel_launch(void* const* d_in, const int* in_sizes, int n_in,
                              void* d_out, int out_size, void* d_ws, size_t ws_size,
                              hipStream_t stream) {
  const float* X    = (const float*)d_in[0];
  const float* A    = (const float*)d_in[1];
  const float* Aaff = (const float*)d_in[2];
  const float* baff = (const float*)d_in[3];
  float* out = (float*)d_out;

  char* w = (char*)d_ws;
  size_t off = 0;
  unsigned short* ATf = (unsigned short*)(w + off); off += (size_t)8 * 8 * 256 * 64 * 8 * 2; // 16 MiB
  unsigned short* Zf  = (unsigned short*)(w + off); off += (size_t)N_PTS * DIM * 2;          // 2 MiB
  float* erow  = (float*)(w + off); off += (size_t)N_PTS * 4;
  float* eperm = (float*)(w + off); off += (size_t)N_PTS * 4;
  float* Zf32 = (float*)(w + off); off += (size_t)N_PTS * DIM * 4;                           // 4 MiB
  unsigned short* Opart = (unsigned short*)(w + off); off += (size_t)8 * N_PTS * DIM * 2;    // 16 MiB
  (void)ws_size; (void)in_sizes; (void)n_in; (void)out_size;

  k_prep<<<dim3(64, 8, 8), 256, 0, stream>>>(A, ATf);
  k_init<<<512, 256, 0, stream>>>(X, Zf, erow, eperm);

  const float* zin = X;
  for (int t = 0; t < 8; ++t) {
    float* zout = (t == 7) ? out : Zf32;  // in-place safe after t=0
    k_flash<<<dim3(8, 64), 256, 0, stream>>>(
        Zf, erow, eperm, ATf + (size_t)t * (8 * 256 * 64 * 8), Aaff + (size_t)t * DIM * DIM, Opart);
    k_update<<<512, 256, 0, stream>>>(zin, Opart, baff + (size_t)t * DIM, zout, Zf, erow, eperm);
    zin = zout;
  }
}

// Round 5
// 434.138 us; speedup vs baseline: 1.9303x; 1.0583x over previous
//
#include <hip/hip_runtime.h>

// DiffeomorphicLearnerTorch, R10 (resubmit — previous attempt hit an
// MI355X container infra failure; kernel never ran).
// R9 FAILED correctness (absmax 6.57, nondeterministic across runs) after
// bundling {log2-domain weights + exp2f} with {asm cvt_pk pack, bw split,
// setprio}. Bisection: only the log2 cluster changed computed VALUES (the
// pack+permlane path was verified bit-exact in R7; bw split reads the same
// constant data; setprio is scheduling-only). R10 = R8's exact verified math
// (natural expf, eperm) + cvt_pk pack (R7-verified) + bw split around the
// S-chain + setprio. Value-identical to R8 by construction.
// Cost model: R8 per-tile VALU ~264 instr/wave, pack = 144 of it; cvt_pk
// cuts pack to 16. bw loads moved pre-S-chain (~600cyc cover vs ~400).
// Structure (R8): per-wave S^T = mfma(A=Zj_lds, B=Zi_regs), P lane-local,
// cvt_pk+permlane32_swap feeds PV directly; Zj double-buffered via
// global_load_lds, one barrier per 32-j tile.
// Wave = 32 i-rows x 128 d-cols; block = 4 waves; grid (8 chunks, 64
// i-blocks) = 512 blocks, 2 blocks/CU (regs ~212/wave).
// Frag-linear layouts (verified R4/R5):
//   Zf  [128 jblk][16 ks][64 lane]x8 bf16
//   ATf [t][8 dblk][256 jb][64 lane]x8 bf16
// eperm = erow permuted to S^T reg order (pidx).

#define N_PTS 4096
#define DIM   256
#define DT_C  0.125f
#define C1    (1.0f/512.0f)
#define C2    (1.0f/256.0f)

typedef __bf16 bf16x8 __attribute__((ext_vector_type(8)));
typedef float  f32x16 __attribute__((ext_vector_type(16)));
typedef float  f32x4v __attribute__((ext_vector_type(4)));
typedef unsigned int   u32x4 __attribute__((ext_vector_type(4)));
typedef unsigned short u16x8 __attribute__((ext_vector_type(8)));

__device__ __forceinline__ unsigned short f2bf(float f) {
  unsigned int u = __builtin_bit_cast(unsigned int, f);
  u += 0x7fffu + ((u >> 16) & 1u);          // RNE
  return (unsigned short)(u >> 16);
}
__device__ __forceinline__ float bf2f(unsigned short s) {
  unsigned int u = ((unsigned int)s) << 16;
  return __builtin_bit_cast(float, u);
}

typedef __attribute__((address_space(1))) const unsigned int gas_u32;
typedef __attribute__((address_space(3))) unsigned int las_u32;
__device__ __forceinline__ void gload_lds16(const void* g, void* l) {
  __builtin_amdgcn_global_load_lds((gas_u32*)g, (las_u32*)l, 16, 0, 0);
}

// ---- ATf: A[t][4096][256] f32 -> frag-linear bf16 B-operand tiles ----
__global__ __launch_bounds__(256) void k_prep(const float* __restrict__ A,
                                              unsigned short* __restrict__ ATf) {
  __shared__ float sT[64][36];
  const int jgrp = blockIdx.x, ds = blockIdx.y, t = blockIdx.z;
  const int tid = threadIdx.x;
  const float* Ab = A + (size_t)t * N_PTS * DIM;
  {
    const int j_l = tid >> 2, dq = tid & 3;
    const float* src = Ab + (size_t)(jgrp * 64 + j_l) * DIM + ds * 32 + dq * 8;
    f32x4v v0 = *(const f32x4v*)src, v1 = *(const f32x4v*)(src + 4);
    *(f32x4v*)&sT[j_l][dq * 8] = v0;
    *(f32x4v*)&sT[j_l][dq * 8 + 4] = v1;
  }
  __syncthreads();
  const int jb_l = tid >> 6, l = tid & 63, l31 = l & 31, lhi = l >> 5;
  u16x8 o;
#pragma unroll
  for (int e = 0; e < 8; ++e) o[e] = f2bf(sT[jb_l * 16 + lhi * 8 + e][l31]);
  unsigned short* dst = ATf + (size_t)t * (8 * 256 * 64 * 8)
                      + ((size_t)(ds * 256 + jgrp * 4 + jb_l) * 64 + l) * 8;
  *(u16x8*)dst = o;
}

// eperm index for row r
__device__ __forceinline__ int pidx(int r) {
  const int jj = r & 31;
  return (r & ~31) | (((jj >> 2) & 1) << 4) | (((jj >> 3) & 3) << 2) | (jj & 3);
}

// ---- init: X -> Zf frags + erow + eperm ----
__global__ __launch_bounds__(256) void k_init(const float* __restrict__ X,
                                              unsigned short* __restrict__ Zf,
                                              float* __restrict__ erow,
                                              float* __restrict__ eperm) {
  const int tid = threadIdx.x;
  const int r = blockIdx.x * 8 + (tid >> 5), o = tid & 31;
  const size_t base = (size_t)r * DIM + o * 8;
  f32x4v z0 = *(const f32x4v*)(X + base), z1 = *(const f32x4v*)(X + base + 4);
  u16x8 zb; float s = 0.f;
#pragma unroll
  for (int i = 0; i < 4; ++i) { zb[i] = f2bf(z0[i]); zb[4 + i] = f2bf(z1[i]);
                                s += z0[i] * z0[i] + z1[i] * z1[i]; }
  *(u16x8*)(Zf + ((size_t)((r >> 5) * 16 + (o >> 1)) * 64 + (o & 1) * 32 + (r & 31)) * 8) = zb;
#pragma unroll
  for (int d = 16; d > 0; d >>= 1) s += __shfl_down(s, d, 32);
  if (o == 0) { const float e = __expf(-s * C1); erow[r] = e; eperm[pidx(r)] = e; }
}

// ---- fused flash, R10 ----
// grid (8 chunks, 64 i-blocks), 256 thr = 4 waves: ig=wid>>1 (32 i-rows),
// dh=wid&1 (128 d-cols). Zi resident in VGPRs (static indices only).
// Zj double-buffered in LDS (16KB/tile, global_load_lds). One barrier/tile.
__global__ __launch_bounds__(256, 2) void k_flash(
    const unsigned short* __restrict__ Zf, const float* __restrict__ erow,
    const float* __restrict__ eperm,
    const unsigned short* __restrict__ ATf_t,
    const float* __restrict__ Aaff_t,
    unsigned short* __restrict__ Opart) {
  __shared__ __align__(16) unsigned short sZj[2][16 * 64 * 8];  // 2 x 16KB

  const int tid = threadIdx.x, lane = tid & 63, wid = tid >> 6;
  const int l31 = lane & 31, lhi = lane >> 5;
  const int ig = wid >> 1, dh = wid & 1;
  const int chunk = blockIdx.x;
  const int i0 = blockIdx.y * 64;

  // stage tile 0 of this chunk's Zj into buf 0 (16KB: 4 x 16B per thread)
  {
    const unsigned short* src = Zf + (size_t)(chunk * 16) * 8192;
#pragma unroll
    for (int p = 0; p < 4; ++p)
      gload_lds16(src + (size_t)(p * 256 + tid) * 8, &sZj[0][(p * 256 + tid) * 8]);
  }

  // resident Zi frags: wave's 32 i-rows x K=256 (static indices ONLY)
  const unsigned short* zib = Zf + (size_t)(blockIdx.y * 2 + ig) * 8192;
  u32x4 zi[16];
#pragma unroll
  for (int ks = 0; ks < 16; ++ks)
    zi[ks] = *(const u32x4*)(zib + (size_t)ks * 512 + lane * 8);

  const float eI = erow[i0 + ig * 32 + l31];

  // O init + affine slice (ksg = chunk*2+q, unscaled; summed across chunks).
  // a-frag re-read from GLOBAL: zi[runtime] would demote zi[] to scratch (R7).
  f32x16 O[4];
#pragma unroll
  for (int ct = 0; ct < 4; ++ct)
#pragma unroll
    for (int i = 0; i < 16; ++i) O[ct][i] = 0.f;
#pragma unroll
  for (int q = 0; q < 2; ++q) {
    const int ksg = chunk * 2 + q;
    const bf16x8 a = *(const bf16x8*)(zib + (size_t)ksg * 512 + lane * 8);
#pragma unroll
    for (int ct = 0; ct < 4; ++ct) {
      const int d = dh * 128 + ct * 32 + l31;
      const float* bp = Aaff_t + (size_t)d * DIM + ksg * 16 + lhi * 8;
      f32x4v f0 = *(const f32x4v*)bp, f1 = *(const f32x4v*)(bp + 4);
      u16x8 tb;
#pragma unroll
      for (int i = 0; i < 4; ++i) { tb[i] = f2bf(f0[i]); tb[4 + i] = f2bf(f1[i]); }
      O[ct] = __builtin_amdgcn_mfma_f32_32x32x16_bf16(
          a, __builtin_bit_cast(bf16x8, tb), O[ct], 0, 0, 0);
    }
  }
  __syncthreads();

  const float* epc = eperm + (size_t)chunk * 512 + lhi * 16;
  const unsigned short* atb =
      ATf_t + ((size_t)(dh * 4 * 256 + chunk * 32) * 64 + lane) * 8;

  for (int n = 0; n < 16; ++n) {
    const int cur = n & 1;
    // prefetch next Zj tile into other buffer (overlaps this tile's compute)
    if (n < 15) {
      const unsigned short* src = Zf + (size_t)(chunk * 16 + n + 1) * 8192;
#pragma unroll
      for (int p = 0; p < 4; ++p)
        gload_lds16(src + (size_t)(p * 256 + tid) * 8,
                    &sZj[cur ^ 1][(p * 256 + tid) * 8]);
    }
    // ej hoist (16 regs) + bw batch q=0: issued BEFORE S-chain so the
    // ~300-500cyc L2 latency hides under ~600cyc of MFMA issue.
    f32x4v e0 = *(const f32x4v*)(epc + n * 32);
    f32x4v e1 = *(const f32x4v*)(epc + n * 32 + 4);
    f32x4v e2 = *(const f32x4v*)(epc + n * 32 + 8);
    f32x4v e3 = *(const f32x4v*)(epc + n * 32 + 12);
    u32x4 bw0[4];
#pragma unroll
    for (int ct = 0; ct < 4; ++ct)
      bw0[ct] = *(const u32x4*)(atb + ((size_t)ct * 256 + n * 2 + 0) * 512);

    // S^T = Zj @ Zi^T : A=Zj (LDS), B=Zi (regs); 2 chains to halve dep depth
    f32x16 Sa, Sb;
#pragma unroll
    for (int i = 0; i < 16; ++i) { Sa[i] = 0.f; Sb[i] = 0.f; }
    __builtin_amdgcn_s_setprio(1);
#pragma unroll
    for (int ks = 0; ks < 16; ks += 2) {
      bf16x8 a0 = *(const bf16x8*)(&sZj[cur][(ks + 0) * 512 + lane * 8]);
      bf16x8 a1 = *(const bf16x8*)(&sZj[cur][(ks + 1) * 512 + lane * 8]);
      Sa = __builtin_amdgcn_mfma_f32_32x32x16_bf16(
          a0, __builtin_bit_cast(bf16x8, zi[ks + 0]), Sa, 0, 0, 0);
      Sb = __builtin_amdgcn_mfma_f32_32x32x16_bf16(
          a1, __builtin_bit_cast(bf16x8, zi[ks + 1]), Sb, 0, 0, 0);
    }
    __builtin_amdgcn_s_setprio(0);

    // bw batch q=1 issued now — latency hides under exp/pack VALU
    u32x4 bw1[4];
#pragma unroll
    for (int ct = 0; ct < 4; ++ct)
      bw1[ct] = *(const u32x4*)(atb + ((size_t)ct * 256 + n * 2 + 1) * 512);

    // P^T: lane=(i,lhi), reg c -> j = n*32 + (c&3)+8*(c>>2)+4*lhi.
    // R8 math (eI*ej*expf), R7-verified cvt_pk pack (static-indexed p[16]).
    float p[16];
#pragma unroll
    for (int c = 0; c < 16; ++c) {
      const float ej = (c < 4) ? e0[c] : (c < 8) ? e1[c - 4]
                     : (c < 12) ? e2[c - 8] : e3[c - 12];
      p[c] = eI * ej * __expf((Sa[c] + Sb[c]) * C2);
    }
    unsigned int dw[4][2];
#pragma unroll
    for (int g = 0; g < 4; ++g) {
      asm("v_cvt_pk_bf16_f32 %0, %1, %2" : "=v"(dw[g][0]) : "v"(p[4 * g + 0]), "v"(p[4 * g + 1]));
      asm("v_cvt_pk_bf16_f32 %0, %1, %2" : "=v"(dw[g][1]) : "v"(p[4 * g + 2]), "v"(p[4 * g + 3]));
    }
    // permlane32_swap: x_new={x_lo,y_lo} -> frag words (e0..3), y_new -> (e4..7)
    {
      auto r0 = __builtin_amdgcn_permlane32_swap(dw[0][0], dw[1][0], false, false);
      auto r1 = __builtin_amdgcn_permlane32_swap(dw[0][1], dw[1][1], false, false);
      u32x4 paw; paw[0] = r0[0]; paw[1] = r1[0]; paw[2] = r0[1]; paw[3] = r1[1];
      const bf16x8 pa = __builtin_bit_cast(bf16x8, paw);
      __builtin_amdgcn_s_setprio(1);
#pragma unroll
      for (int ct = 0; ct < 4; ++ct)
        O[ct] = __builtin_amdgcn_mfma_f32_32x32x16_bf16(
            pa, __builtin_bit_cast(bf16x8, bw0[ct]), O[ct], 0, 0, 0);
      __builtin_amdgcn_s_setprio(0);
    }
    {
      auto r0 = __builtin_amdgcn_permlane32_swap(dw[2][0], dw[3][0], false, false);
      auto r1 = __builtin_amdgcn_permlane32_swap(dw[2][1], dw[3][1], false, false);
      u32x4 paw; paw[0] = r0[0]; paw[1] = r1[0]; paw[2] = r0[1]; paw[3] = r1[1];
      const bf16x8 pa = __builtin_bit_cast(bf16x8, paw);
      __builtin_amdgcn_s_setprio(1);
#pragma unroll
      for (int ct = 0; ct < 4; ++ct)
        O[ct] = __builtin_amdgcn_mfma_f32_32x32x16_bf16(
            pa, __builtin_bit_cast(bf16x8, bw1[ct]), O[ct], 0, 0, 0);
      __builtin_amdgcn_s_setprio(0);
    }
    __syncthreads();  // next tile staged (vmcnt drain) + all reads of cur done
  }

  // epilogue -> Opart[chunk] bf16 (P already carries ei*ej)
  unsigned short* ob = Opart + (size_t)chunk * N_PTS * DIM
                     + (size_t)(i0 + ig * 32) * DIM + dh * 128 + l31;
#pragma unroll
  for (int ct = 0; ct < 4; ++ct)
#pragma unroll
    for (int c = 0; c < 16; ++c) {
      const int row = 4 * lhi + (c & 3) + 8 * (c >> 2);
      ob[(size_t)row * DIM + ct * 32] = f2bf(O[ct][c]);
    }
}

// ---- update: Z += DT*(sum partials + baff); emit Zf frags + erow + eperm ----
__global__ __launch_bounds__(256) void k_update(const float* __restrict__ Zin,
                                                const unsigned short* __restrict__ Opart,
                                                const float* __restrict__ baff_t,
                                                float* __restrict__ Zout,
                                                unsigned short* __restrict__ Zf,
                                                float* __restrict__ erow,
                                                float* __restrict__ eperm) {
  const int tid = threadIdx.x;
  const int r = blockIdx.x * 8 + (tid >> 5), o = tid & 31;
  const size_t base = (size_t)r * DIM + o * 8;
  f32x4v z0 = *(const f32x4v*)(Zin + base), z1 = *(const f32x4v*)(Zin + base + 4);
  f32x4v s0 = *(const f32x4v*)(baff_t + o * 8), s1 = *(const f32x4v*)(baff_t + o * 8 + 4);
#pragma unroll
  for (int c = 0; c < 8; ++c) {
    u16x8 p = *(const u16x8*)(Opart + (size_t)c * N_PTS * DIM + base);
#pragma unroll
    for (int i = 0; i < 4; ++i) { s0[i] += bf2f(p[i]); s1[i] += bf2f(p[4 + i]); }
  }
  u16x8 zb; float sv = 0.f;
#pragma unroll
  for (int i = 0; i < 4; ++i) {
    z0[i] += DT_C * s0[i]; z1[i] += DT_C * s1[i];
    zb[i] = f2bf(z0[i]); zb[4 + i] = f2bf(z1[i]);
    sv += z0[i] * z0[i] + z1[i] * z1[i];
  }
  *(f32x4v*)(Zout + base) = z0;
  *(f32x4v*)(Zout + base + 4) = z1;
  *(u16x8*)(Zf + ((size_t)((r >> 5) * 16 + (o >> 1)) * 64 + (o & 1) * 32 + (r & 31)) * 8) = zb;
#pragma unroll
  for (int d = 16; d > 0; d >>= 1) sv += __shfl_down(sv, d, 32);
  if (o == 0) { const float e = __expf(-sv * C1); erow[r] = e; eperm[pidx(r)] = e; }
}

extern "C" void kernel_launch(void* const* d_in, const int* in_sizes, int n_in,
                              void* d_out, int out_size, void* d_ws, size_t ws_size,
                              hipStream_t stream) {
  const float* X    = (const float*)d_in[0];
  const float* A    = (const float*)d_in[1];
  const float* Aaff = (const float*)d_in[2];
  const float* baff = (const float*)d_in[3];
  float* out = (float*)d_out;

  char* w = (char*)d_ws;
  size_t off = 0;
  unsigned short* ATf = (unsigned short*)(w + off); off += (size_t)8 * 8 * 256 * 64 * 8 * 2; // 16 MiB
  unsigned short* Zf  = (unsigned short*)(w + off); off += (size_t)N_PTS * DIM * 2;          // 2 MiB
  float* erow  = (float*)(w + off); off += (size_t)N_PTS * 4;
  float* eperm = (float*)(w + off); off += (size_t)N_PTS * 4;
  float* Zf32 = (float*)(w + off); off += (size_t)N_PTS * DIM * 4;                           // 4 MiB
  unsigned short* Opart = (unsigned short*)(w + off); off += (size_t)8 * N_PTS * DIM * 2;    // 16 MiB
  (void)ws_size; (void)in_sizes; (void)n_in; (void)out_size;

  k_prep<<<dim3(64, 8, 8), 256, 0, stream>>>(A, ATf);
  k_init<<<512, 256, 0, stream>>>(X, Zf, erow, eperm);

  const float* zin = X;
  for (int t = 0; t < 8; ++t) {
    float* zout = (t == 7) ? out : Zf32;  // in-place safe after t=0
    k_flash<<<dim3(8, 64), 256, 0, stream>>>(
        Zf, erow, eperm, ATf + (size_t)t * (8 * 256 * 64 * 8), Aaff + (size_t)t * DIM * DIM, Opart);
    k_update<<<512, 256, 0, stream>>>(zin, Opart, baff + (size_t)t * DIM, zout, Zf, erow, eperm);
    zin = zout;
  }
}